// Round 2
// baseline (4860.201 us; speedup 1.0000x reference)
//
#include <hip/hip_runtime.h>

#define NN 50000
#define EE 800000

#ifdef __HIP_PLATFORM_AMD__
#define ATOMIC_ADD_F32(p, v) unsafeAtomicAdd((p), (v))
#else
#define ATOMIC_ADD_F32(p, v) atomicAdd((p), (v))
#endif

// ws layout (floats): [0..256) scalars (0=S1, 1=S2); [256..256+NN*96) upd; then node2 (NN*96)

// ---------------- Node GVP: one node per thread.
// s1=LN(relu(gvp_s)+s0), V1=gvp_V+V0 (stored unscaled), accumulate sumsq(V1).
__global__ __launch_bounds__(256) void k_node(
    const float* __restrict__ na,
    const float* __restrict__ Wh,   // 32x16
    const float* __restrict__ Wmu,  // 16x32
    const float* __restrict__ Wmw,  // 48x80
    const float* __restrict__ Wmb,  // 48
    const float* __restrict__ lng,
    const float* __restrict__ lnb,
    float* __restrict__ node2,
    float* __restrict__ S1)
{
    int n = blockIdx.x * 256 + threadIdx.x;
    float ss = 0.f;
    if (n < NN) {
        const float* row = na + (long)n * 96;
        float vmu[48], sh[32];
        #pragma unroll
        for (int h = 0; h < 32; h++) sh[h] = 0.f;
        #pragma unroll
        for (int d = 0; d < 3; d++) {
            float vc[16];
            #pragma unroll
            for (int v = 0; v < 16; v++) vc[v] = row[48 + v*3 + d];
            float vh[32];
            #pragma unroll
            for (int h = 0; h < 32; h++) {
                float a = 0.f;
                #pragma unroll
                for (int v = 0; v < 16; v++) a += Wh[h*16 + v] * vc[v];
                vh[h] = a;
                sh[h] += a * a;
            }
            #pragma unroll
            for (int m = 0; m < 16; m++) {
                float a = 0.f;
                #pragma unroll
                for (int h = 0; h < 32; h++) a += Wmu[m*32 + h] * vh[h];
                vmu[m*3 + d] = a;
            }
        }
        // scalar path
        float x[80];
        {
            const float4* r4 = (const float4*)row;
            #pragma unroll
            for (int q = 0; q < 12; q++) {
                float4 f = r4[q];
                x[q*4] = f.x; x[q*4+1] = f.y; x[q*4+2] = f.z; x[q*4+3] = f.w;
            }
            #pragma unroll
            for (int h = 0; h < 32; h++) x[48 + h] = sqrtf(sh[h]);
        }
        float s1[48];
        #pragma unroll
        for (int i = 0; i < 48; i++) {
            float a = Wmb[i];
            #pragma unroll
            for (int k = 0; k < 80; k++) a += Wmw[i*80 + k] * x[k];
            s1[i] = fmaxf(a, 0.f) + x[i];
        }
        float mean = 0.f;
        #pragma unroll
        for (int i = 0; i < 48; i++) mean += s1[i];
        mean *= (1.f/48.f);
        float var = 0.f;
        #pragma unroll
        for (int i = 0; i < 48; i++) { float d = s1[i] - mean; var += d*d; }
        float inv = rsqrtf(var*(1.f/48.f) + 1e-5f);
        float* o = node2 + (long)n * 96;
        #pragma unroll
        for (int i = 0; i < 48; i++)
            o[i] = (s1[i] - mean) * inv * lng[i] + lnb[i];
        #pragma unroll
        for (int m = 0; m < 16; m++) {
            float a = vmu[m*3], b = vmu[m*3+1], c = vmu[m*3+2];
            float nm = sqrtf(a*a + b*b + c*c);
            float xx = nm*a + row[48 + m*3 + 0];
            float yy = nm*b + row[48 + m*3 + 1];
            float zz = nm*c + row[48 + m*3 + 2];
            o[48 + m*3 + 0] = xx; o[48 + m*3 + 1] = yy; o[48 + m*3 + 2] = zz;
            ss += xx*xx + yy*yy + zz*zz;
        }
    }
    #pragma unroll
    for (int off = 32; off > 0; off >>= 1) ss += __shfl_down(ss, off, 64);
    if ((threadIdx.x & 63) == 0) atomicAdd(S1, ss);
}

// ---------------- scale node2 V-part by global gvp_ln factor
__global__ void k_scale(float* __restrict__ node2, const float* __restrict__ S1)
{
    int i = blockIdx.x*256 + threadIdx.x;
    if (i < NN*48) {
        float scale = rsqrtf(sqrtf(*S1) * (1.f/16.f));
        int n = i/48, p = i%48;
        node2[(long)n*96 + 48 + p] *= scale;
    }
}

// ---------------- Edge kernel: one edge per thread.
// gve GVP -> atomic scatter into upd; ge GVP -> out1.
// Weights read via wave-uniform addresses -> s_load (scalar cache), inputs in VGPRs.
__global__ __launch_bounds__(256) void k_edge(
    const float* __restrict__ ea, const int* __restrict__ eidx,
    const float* __restrict__ node2,
    const float* __restrict__ gveWh,  // 32x32
    const float* __restrict__ gveWmu, // 16x32
    const float* __restrict__ gveWmw, // 48x112
    const float* __restrict__ gveWmb, // 48
    const float* __restrict__ geWh,   // 32x32
    const float* __restrict__ geWmu,  // 16x32
    const float* __restrict__ geWmw,  // 32x112
    const float* __restrict__ geWmb,  // 32
    float* __restrict__ upd, float* __restrict__ out1)
{
    int e = blockIdx.x * 256 + threadIdx.x;   // EE % 256 == 0
    int dst = eidx[e];
    int src = eidx[EE + e];
    const float* nrow = node2 + (long)src * 96;
    const float* erow = ea + (long)e * 80;
    float* urow = upd + (long)dst * 96;
    float* orow = out1 + (long)e * 80;

    // ================= gve: V phase =================
    {
        float vmu[48], sh[32];
        #pragma unroll
        for (int h = 0; h < 32; h++) sh[h] = 0.f;
        #pragma unroll
        for (int d = 0; d < 3; d++) {
            float vc[32];
            #pragma unroll
            for (int v = 0; v < 16; v++) vc[v] = nrow[48 + v*3 + d];
            #pragma unroll
            for (int v = 0; v < 16; v++) vc[16+v] = erow[32 + v*3 + d];
            float vh[32];
            #pragma unroll
            for (int h = 0; h < 32; h++) {
                float a = 0.f;
                #pragma unroll
                for (int v = 0; v < 32; v++) a += gveWh[h*32 + v] * vc[v];
                vh[h] = a;
                sh[h] += a * a;
            }
            #pragma unroll
            for (int m = 0; m < 16; m++) {
                float a = 0.f;
                #pragma unroll
                for (int h = 0; h < 32; h++) a += gveWmu[m*32 + h] * vh[h];
                vmu[m*3 + d] = a;
            }
        }
        // vector message: |Vmu| * Vmu  (relu(|.|) == |.|)
        #pragma unroll
        for (int m = 0; m < 16; m++) {
            float a = vmu[m*3], b = vmu[m*3+1], c = vmu[m*3+2];
            float nm = sqrtf(a*a + b*b + c*c);
            ATOMIC_ADD_F32(&urow[48 + m*3 + 0], nm*a);
            ATOMIC_ADD_F32(&urow[48 + m*3 + 1], nm*b);
            ATOMIC_ADD_F32(&urow[48 + m*3 + 2], nm*c);
        }
        // ---- gve scalar phase ----
        float x[112];
        {
            const float4* n4 = (const float4*)nrow;
            #pragma unroll
            for (int q = 0; q < 12; q++) {
                float4 f = n4[q];
                x[q*4] = f.x; x[q*4+1] = f.y; x[q*4+2] = f.z; x[q*4+3] = f.w;
            }
            const float4* e4 = (const float4*)erow;
            #pragma unroll
            for (int q = 0; q < 8; q++) {
                float4 f = e4[q];
                x[48+q*4] = f.x; x[48+q*4+1] = f.y; x[48+q*4+2] = f.z; x[48+q*4+3] = f.w;
            }
            #pragma unroll
            for (int h = 0; h < 32; h++) x[80 + h] = sqrtf(sh[h]);
        }
        for (int i0 = 0; i0 < 48; i0 += 4) {       // i0 uniform -> s_load weights
            float a0 = gveWmb[i0+0], a1 = gveWmb[i0+1], a2 = gveWmb[i0+2], a3 = gveWmb[i0+3];
            #pragma unroll
            for (int k = 0; k < 112; k++) {
                float xv = x[k];
                a0 += gveWmw[(i0+0)*112 + k] * xv;
                a1 += gveWmw[(i0+1)*112 + k] * xv;
                a2 += gveWmw[(i0+2)*112 + k] * xv;
                a3 += gveWmw[(i0+3)*112 + k] * xv;
            }
            ATOMIC_ADD_F32(&urow[i0+0], fmaxf(a0, 0.f));
            ATOMIC_ADD_F32(&urow[i0+1], fmaxf(a1, 0.f));
            ATOMIC_ADD_F32(&urow[i0+2], fmaxf(a2, 0.f));
            ATOMIC_ADD_F32(&urow[i0+3], fmaxf(a3, 0.f));
        }
    }

    // ================= ge: V phase =================
    {
        float vmu[48], sh[32];
        #pragma unroll
        for (int h = 0; h < 32; h++) sh[h] = 0.f;
        #pragma unroll
        for (int d = 0; d < 3; d++) {
            float vc[32];
            #pragma unroll
            for (int v = 0; v < 16; v++) vc[v] = nrow[48 + v*3 + d];     // L1-hot reload
            #pragma unroll
            for (int v = 0; v < 16; v++) vc[16+v] = erow[32 + v*3 + d];
            float vh[32];
            #pragma unroll
            for (int h = 0; h < 32; h++) {
                float a = 0.f;
                #pragma unroll
                for (int v = 0; v < 32; v++) a += geWh[h*32 + v] * vc[v];
                vh[h] = a;
                sh[h] += a * a;
            }
            #pragma unroll
            for (int m = 0; m < 16; m++) {
                float a = 0.f;
                #pragma unroll
                for (int h = 0; h < 32; h++) a += geWmu[m*32 + h] * vh[h];
                vmu[m*3 + d] = a;
            }
        }
        #pragma unroll
        for (int m = 0; m < 16; m++) {
            float a = vmu[m*3], b = vmu[m*3+1], c = vmu[m*3+2];
            float nm = sqrtf(a*a + b*b + c*c);
            orow[32 + m*3 + 0] = nm*a;
            orow[32 + m*3 + 1] = nm*b;
            orow[32 + m*3 + 2] = nm*c;
        }
        // ---- ge scalar phase ----
        float x[112];
        {
            const float4* n4 = (const float4*)nrow;
            #pragma unroll
            for (int q = 0; q < 12; q++) {
                float4 f = n4[q];
                x[q*4] = f.x; x[q*4+1] = f.y; x[q*4+2] = f.z; x[q*4+3] = f.w;
            }
            const float4* e4 = (const float4*)erow;
            #pragma unroll
            for (int q = 0; q < 8; q++) {
                float4 f = e4[q];
                x[48+q*4] = f.x; x[48+q*4+1] = f.y; x[48+q*4+2] = f.z; x[48+q*4+3] = f.w;
            }
            #pragma unroll
            for (int h = 0; h < 32; h++) x[80 + h] = sqrtf(sh[h]);
        }
        for (int i0 = 0; i0 < 32; i0 += 4) {
            float a0 = geWmb[i0+0], a1 = geWmb[i0+1], a2 = geWmb[i0+2], a3 = geWmb[i0+3];
            #pragma unroll
            for (int k = 0; k < 112; k++) {
                float xv = x[k];
                a0 += geWmw[(i0+0)*112 + k] * xv;
                a1 += geWmw[(i0+1)*112 + k] * xv;
                a2 += geWmw[(i0+2)*112 + k] * xv;
                a3 += geWmw[(i0+3)*112 + k] * xv;
            }
            orow[i0+0] = fmaxf(a0, 0.f);
            orow[i0+1] = fmaxf(a1, 0.f);
            orow[i0+2] = fmaxf(a2, 0.f);
            orow[i0+3] = fmaxf(a3, 0.f);
        }
    }
}

// ---------------- node update: su=LN(upd_s/30+s1), Vu=upd_V/30+V1 (stash unscaled), sumsq
__global__ __launch_bounds__(256) void k_update(
    const float* __restrict__ upd, const float* __restrict__ node2,
    const float* __restrict__ lng, const float* __restrict__ lnb,
    float* __restrict__ out0, float* __restrict__ S2)
{
    int n = blockIdx.x*256 + threadIdx.x;
    float ss = 0.f;
    if (n < NN) {
        const float* u = upd + (long)n*96;
        const float* p2 = node2 + (long)n*96;
        float su[48];
        float mean = 0.f;
        #pragma unroll
        for (int i = 0; i < 48; i++) { float v = u[i]*(1.f/30.f) + p2[i]; su[i] = v; mean += v; }
        mean *= (1.f/48.f);
        float var = 0.f;
        #pragma unroll
        for (int i = 0; i < 48; i++) { float d = su[i] - mean; var += d*d; }
        float inv = rsqrtf(var*(1.f/48.f) + 1e-5f);
        float* o = out0 + (long)n*96;
        #pragma unroll
        for (int i = 0; i < 48; i++) o[i] = p2[i] + (su[i]-mean)*inv*lng[i] + lnb[i];
        #pragma unroll
        for (int p = 0; p < 48; p++) {
            float v = u[48+p]*(1.f/30.f) + p2[48+p];
            o[48+p] = v;           // stash unscaled Vu
            ss += v*v;
        }
    }
    #pragma unroll
    for (int off = 32; off > 0; off >>= 1) ss += __shfl_down(ss, off, 64);
    if ((threadIdx.x & 63) == 0) atomicAdd(S2, ss);
}

// ---------------- finalize V part of output 0
__global__ void k_fin(float* __restrict__ out0, const float* __restrict__ node2,
                      const float* __restrict__ S2)
{
    int i = blockIdx.x*256 + threadIdx.x;
    if (i < NN*48) {
        float scale = rsqrtf(sqrtf(*S2) * (1.f/16.f));
        int n = i/48, p = i%48;
        long off = (long)n*96 + 48 + p;
        out0[off] = node2[off] + out0[off]*scale;
    }
}

extern "C" void kernel_launch(void* const* d_in, const int* in_sizes, int n_in,
                              void* d_out, int out_size, void* d_ws, size_t ws_size,
                              hipStream_t stream)
{
    const float* na      = (const float*)d_in[0];
    const float* ea      = (const float*)d_in[1];
    const int*   eidx    = (const int*)  d_in[2];
    const float* gv_Wh   = (const float*)d_in[3];
    const float* gv_Wmu  = (const float*)d_in[4];
    const float* gv_Wmw  = (const float*)d_in[5];
    const float* gv_Wmb  = (const float*)d_in[6];
    const float* gve_Wh  = (const float*)d_in[7];
    const float* gve_Wmu = (const float*)d_in[8];
    const float* gve_Wmw = (const float*)d_in[9];
    const float* gve_Wmb = (const float*)d_in[10];
    const float* ge_Wh   = (const float*)d_in[11];
    const float* ge_Wmu  = (const float*)d_in[12];
    const float* ge_Wmw  = (const float*)d_in[13];
    const float* ge_Wmb  = (const float*)d_in[14];
    const float* lng     = (const float*)d_in[15];
    const float* lnb     = (const float*)d_in[16];

    float* ws    = (float*)d_ws;
    float* S     = ws;                         // [0]=S1, [1]=S2
    float* upd   = ws + 256;
    float* node2 = ws + 256 + (size_t)NN*96;
    float* out0  = (float*)d_out;
    float* out1  = out0 + (size_t)NN*96;

    // zero scalars + upd accumulator (ws is poisoned 0xAA before every launch)
    hipMemsetAsync(d_ws, 0, (256 + (size_t)NN*96) * sizeof(float), stream);

    k_node<<<(NN + 255)/256, 256, 0, stream>>>(na, gv_Wh, gv_Wmu, gv_Wmw, gv_Wmb,
                                               lng, lnb, node2, S);
    k_scale<<<(NN*48 + 255)/256, 256, 0, stream>>>(node2, S);
    k_edge<<<EE/256, 256, 0, stream>>>(ea, eidx, node2,
                                       gve_Wh, gve_Wmu, gve_Wmw, gve_Wmb,
                                       ge_Wh, ge_Wmu, ge_Wmw, ge_Wmb,
                                       upd, out1);
    k_update<<<(NN + 255)/256, 256, 0, stream>>>(upd, node2, lng, lnb, out0, S + 1);
    k_fin<<<(NN*48 + 255)/256, 256, 0, stream>>>(out0, node2, S + 1);
}